// Round 2
// baseline (139.479 us; speedup 1.0000x reference)
//
#include <hip/hip_runtime.h>
#include <math.h>

#define BB 8
#define HH 16
#define NN 1024
#define QQ 2
#define THREADS 256

__device__ __forceinline__ void upd_min(float& m, float ax, float ay, float az,
                                        float px, float py, float pz) {
    float dx = ax - px, dy = ay - py, dz = az - pz;
    m = fminf(m, dx * dx + dy * dy + dz * dz);
}

// Kernel 1: per-(b,h) symmetric chamfer between reflected points and samples.
// Grid: BB*HH*QQ blocks; block (bh,q) computes complete row-mins for its
// i-chunk and complete col-mins for its j-chunk (both need ALL 1024 opposing
// points, which live in LDS), then atomicAdds the partial sum into sde_acc[bh].
__global__ __launch_bounds__(THREADS) void chamfer_kernel(
    const float* __restrict__ y_pred,
    const float* __restrict__ sp,
    float* __restrict__ sde_acc)
{
    __shared__ __align__(16) float spx[NN], spy[NN], spz[NN];
    __shared__ __align__(16) float rfx[NN], rfy[NN], rfz[NN];
    __shared__ float wsum[THREADS / 64];

    const int blk = blockIdx.x;
    const int q   = blk % QQ;
    const int bh  = blk / QQ;
    const int b   = bh / HH;
    const int tid = threadIdx.x;

    float pnx = y_pred[bh * 4 + 0];
    float pny = y_pred[bh * 4 + 1];
    float pnz = y_pred[bh * 4 + 2];
    float pd  = y_pred[bh * 4 + 3];
    float inv = 1.0f / sqrtf(pnx * pnx + pny * pny + pnz * pnz);
    pnx *= inv; pny *= inv; pnz *= inv;

    const float* spb = sp + (size_t)b * NN * 3;
    for (int p = tid; p < NN; p += THREADS) {
        float x = spb[p * 3 + 0];
        float y = spb[p * 3 + 1];
        float z = spb[p * 3 + 2];
        spx[p] = x; spy[p] = y; spz[p] = z;
        float proj = x * pnx + y * pny + z * pnz + pd;
        rfx[p] = x - 2.0f * proj * pnx;
        rfy[p] = y - 2.0f * proj * pny;
        rfz[p] = z - 2.0f * proj * pnz;
    }
    __syncthreads();

    const int CH = NN / QQ;   // 512
    float local = 0.0f;

    // Pass A: row-mins — thread owns 2 reflected points, scans all samples.
    {
        int i0 = q * CH + tid;
        int i1 = i0 + THREADS;
        float ax = rfx[i0], ay = rfy[i0], az = rfz[i0];
        float bx = rfx[i1], by = rfy[i1], bz = rfz[i1];
        float m0 = 3.4e38f, m1 = 3.4e38f;
        for (int j = 0; j < NN; j += 4) {
            float4 vx = *reinterpret_cast<const float4*>(&spx[j]);
            float4 vy = *reinterpret_cast<const float4*>(&spy[j]);
            float4 vz = *reinterpret_cast<const float4*>(&spz[j]);
            upd_min(m0, ax, ay, az, vx.x, vy.x, vz.x);
            upd_min(m0, ax, ay, az, vx.y, vy.y, vz.y);
            upd_min(m0, ax, ay, az, vx.z, vy.z, vz.z);
            upd_min(m0, ax, ay, az, vx.w, vy.w, vz.w);
            upd_min(m1, bx, by, bz, vx.x, vy.x, vz.x);
            upd_min(m1, bx, by, bz, vx.y, vy.y, vz.y);
            upd_min(m1, bx, by, bz, vx.z, vy.z, vz.z);
            upd_min(m1, bx, by, bz, vx.w, vy.w, vz.w);
        }
        local += m0 + m1;
    }

    // Pass B: col-mins — thread owns 2 sample points, scans all reflections.
    {
        int j0 = q * CH + tid;
        int j1 = j0 + THREADS;
        float ax = spx[j0], ay = spy[j0], az = spz[j0];
        float bx = spx[j1], by = spy[j1], bz = spz[j1];
        float m0 = 3.4e38f, m1 = 3.4e38f;
        for (int i = 0; i < NN; i += 4) {
            float4 vx = *reinterpret_cast<const float4*>(&rfx[i]);
            float4 vy = *reinterpret_cast<const float4*>(&rfy[i]);
            float4 vz = *reinterpret_cast<const float4*>(&rfz[i]);
            upd_min(m0, ax, ay, az, vx.x, vy.x, vz.x);
            upd_min(m0, ax, ay, az, vx.y, vy.y, vz.y);
            upd_min(m0, ax, ay, az, vx.z, vy.z, vz.z);
            upd_min(m0, ax, ay, az, vx.w, vy.w, vz.w);
            upd_min(m1, bx, by, bz, vx.x, vy.x, vz.x);
            upd_min(m1, bx, by, bz, vx.y, vy.y, vz.y);
            upd_min(m1, bx, by, bz, vx.z, vy.z, vz.z);
            upd_min(m1, bx, by, bz, vx.w, vy.w, vz.w);
        }
        local += m0 + m1;
    }

    for (int off = 32; off; off >>= 1) local += __shfl_down(local, off, 64);
    int wid = tid >> 6, lane = tid & 63;
    if (lane == 0) wsum[wid] = local;
    __syncthreads();
    if (tid == 0) {
        float t = 0.0f;
        for (int w = 0; w < THREADS / 64; ++w) t += wsum[w];
        atomicAdd(&sde_acc[bh], t);
    }
}

// Kernel 2: per-batch finalize — centroid, conf, angle-NMS, stable rank, write.
__global__ __launch_bounds__(64) void finalize_kernel(
    const float* __restrict__ sde_acc,
    const float* __restrict__ y_pred,
    const float* __restrict__ sp,
    float* __restrict__ out)
{
    const int b   = blockIdx.x;
    const int tid = threadIdx.x;

    const float* spb = sp + (size_t)b * NN * 3;
    float sx = 0.0f, sy = 0.0f, sz = 0.0f;
    for (int p = tid; p < NN; p += 64) {
        sx += spb[p * 3 + 0];
        sy += spb[p * 3 + 1];
        sz += spb[p * 3 + 2];
    }
    for (int off = 32; off; off >>= 1) {
        sx += __shfl_down(sx, off, 64);
        sy += __shfl_down(sy, off, 64);
        sz += __shfl_down(sz, off, 64);
    }
    sx = __shfl(sx, 0, 64); sy = __shfl(sy, 0, 64); sz = __shfl(sz, 0, 64);
    const float cmx = sx / NN, cmy = sy / NN, cmz = sz / NN;

    __shared__ float sde_s[HH], nx_s[HH], ny_s[HH], nz_s[HH], d_s[HH], conf_s[HH];
    __shared__ int keep_s[HH];

    if (tid < HH) {
        int h = tid;
        float nx = y_pred[(b * HH + h) * 4 + 0];
        float ny = y_pred[(b * HH + h) * 4 + 1];
        float nz = y_pred[(b * HH + h) * 4 + 2];
        float d  = y_pred[(b * HH + h) * 4 + 3];
        float inv = 1.0f / sqrtf(nx * nx + ny * ny + nz * nz);
        nx *= inv; ny *= inv; nz *= inv;
        nx_s[h] = nx; ny_s[h] = ny; nz_s[h] = nz; d_s[h] = d;
        sde_s[h] = sde_acc[b * HH + h] * (1.0f / NN);
    }
    __syncthreads();

    if (tid < HH) {
        int h = tid;
        float mn = sde_s[0], mx = sde_s[0];
        for (int g = 1; g < HH; ++g) {
            mn = fminf(mn, sde_s[g]);
            mx = fmaxf(mx, sde_s[g]);
        }
        float sde  = sde_s[h];
        float conf = 1.0f - (sde - mn) / fabsf(mx - mn);
        conf_s[h]  = conf;
        bool valid = (sde <= 10.0f);
        bool sup   = false;
        if (valid) {
            for (int g = 0; g < HH; ++g) {
                if (g == h) continue;
                float c = nx_s[h] * nx_s[g] + ny_s[h] * ny_s[g] + nz_s[h] * nz_s[g];
                c = fminf(1.0f, fmaxf(-1.0f, c));
                float ang = acosf(c) * 57.29577951308232f;
                bool close = (ang < 30.0f) || (180.0f - ang < 30.0f);
                if (close && (sde_s[g] <= 10.0f) && (sde >= sde_s[g])) sup = true;
            }
        }
        keep_s[h] = (valid && !sup) ? 1 : 0;
    }
    __syncthreads();

    if (tid < HH) {
        int h = tid;
        // stable descending rank on key = keep ? conf : -inf  (jnp.argsort(-key))
        float keyh = keep_s[h] ? conf_s[h] : -INFINITY;
        int pos = 0;
        for (int g = 0; g < HH; ++g) {
            float keyg = keep_s[g] ? conf_s[g] : -INFINITY;
            if (keyg > keyh || (keyg == keyh && g < h)) ++pos;
        }
        float nx = nx_s[h], ny = ny_s[h], nz = nz_s[h];
        float t  = nx * cmx + ny * cmy + nz * cmz + d_s[h];
        float px = cmx - t * nx, py = cmy - t * ny, pz = cmz - t * nz;

        float* o = out + (size_t)(b * HH + pos) * 8;
        if (keep_s[h]) {
            o[0] = nx; o[1] = ny; o[2] = nz;
            o[3] = px; o[4] = py; o[5] = pz;
            o[6] = conf_s[h];
            o[7] = sde_s[h];
        } else {
            for (int c = 0; c < 8; ++c) o[c] = 0.0f;
        }
    }
}

extern "C" void kernel_launch(void* const* d_in, const int* in_sizes, int n_in,
                              void* d_out, int out_size, void* d_ws, size_t ws_size,
                              hipStream_t stream) {
    const float* y_pred = (const float*)d_in[0];   // (B,H,4) float32
    const float* sp     = (const float*)d_in[1];   // (B,N,3) float32
    float* out          = (float*)d_out;           // (B,H,8) float32
    float* sde_ws       = (float*)d_ws;            // BB*HH fp32 accumulators

    hipMemsetAsync(sde_ws, 0, BB * HH * sizeof(float), stream);
    chamfer_kernel<<<dim3(BB * HH * QQ), dim3(THREADS), 0, stream>>>(y_pred, sp, sde_ws);
    finalize_kernel<<<dim3(BB), dim3(64), 0, stream>>>(sde_ws, y_pred, sp, out);
}

// Round 3
// 105.117 us; speedup vs baseline: 1.3269x; 1.3269x over previous
//
#include <hip/hip_runtime.h>
#include <math.h>

#define BB 8
#define HH 16
#define NN 1024
#define TB 256
#define CI 512            // i-chunk per block (refl side)
#define CJ 512            // j-chunk per block (sample side)
#define QI (NN / CI)      // 2
#define QJ (NN / CJ)      // 2

// ws layout (floats):
//   [0, 128)                         : sde sums per (b,h)
//   [WS_ROW, WS_ROW + 128*QJ*NN)     : row-min partials  [(bh*QJ+qj)*NN + i]
//   [WS_COL, WS_COL + 128*QI*NN)     : col-min partials  [(bh*QI+qi)*NN + j]
#define WS_ROW 128
#define WS_COL (128 + BB * HH * QJ * NN)
#define WS_FLOATS (128 + BB * HH * QJ * NN + BB * HH * QI * NN)

// ---------------------------------------------------------------------------
// Split chamfer: block (bh, qi, qj) covers i-chunk x j-chunk. Dot-form:
// d2 = rr_i + (ss_j - 2*dot_ij); min over the scan dim kept in registers,
// rr/ss added at the end (result >= 0). Partials stored to ws, no atomics.
// ---------------------------------------------------------------------------
__global__ __launch_bounds__(TB) void chamfer_split_kernel(
    const float* __restrict__ y_pred,
    const float* __restrict__ sp,
    float* __restrict__ ws)
{
    __shared__ __align__(16) float spx[CJ], spy[CJ], spz[CJ], ssv[CJ];
    __shared__ __align__(16) float rfx[CI], rfy[CI], rfz[CI], rrv[CI];

    const int blk = blockIdx.x;
    const int bh  = blk >> 2;
    const int r   = blk & 3;
    const int qi  = r >> 1;
    const int qj  = r & 1;
    const int b   = bh >> 4;          // HH = 16
    const int tid = threadIdx.x;

    float pnx = y_pred[bh * 4 + 0];
    float pny = y_pred[bh * 4 + 1];
    float pnz = y_pred[bh * 4 + 2];
    float pd  = y_pred[bh * 4 + 3];
    float inv = 1.0f / sqrtf(pnx * pnx + pny * pny + pnz * pnz);
    pnx *= inv; pny *= inv; pnz *= inv;

    const float* spb = sp + (size_t)b * NN * 3;

    // stage sample j-chunk (x,y,z,ss)
    for (int k = 0; k < CJ; k += TB) {
        int jl = k + tid;
        int jg = qj * CJ + jl;
        float x = spb[jg * 3 + 0], y = spb[jg * 3 + 1], z = spb[jg * 3 + 2];
        spx[jl] = x; spy[jl] = y; spz[jl] = z;
        ssv[jl] = x * x + y * y + z * z;
    }
    // stage reflected i-chunk (x,y,z,rr)
    for (int k = 0; k < CI; k += TB) {
        int il = k + tid;
        int ig = qi * CI + il;
        float x = spb[ig * 3 + 0], y = spb[ig * 3 + 1], z = spb[ig * 3 + 2];
        float proj = x * pnx + y * pny + z * pnz + pd;
        float rx = x - 2.0f * proj * pnx;
        float ry = y - 2.0f * proj * pny;
        float rz = z - 2.0f * proj * pnz;
        rfx[il] = rx; rfy[il] = ry; rfz[il] = rz;
        rrv[il] = rx * rx + ry * ry + rz * rz;
    }
    __syncthreads();

    // ---- Pass A: row-min partials. Thread owns refl i_local = tid, tid+TB. ----
    {
        float ax0 = rfx[tid],      ay0 = rfy[tid],      az0 = rfz[tid],      r0 = rrv[tid];
        float ax1 = rfx[tid + TB], ay1 = rfy[tid + TB], az1 = rfz[tid + TB], r1 = rrv[tid + TB];
        float m0a = 3.4e38f, m0b = 3.4e38f, m1a = 3.4e38f, m1b = 3.4e38f;
        for (int j = 0; j < CJ; j += 4) {
            float4 vx = *reinterpret_cast<const float4*>(&spx[j]);
            float4 vy = *reinterpret_cast<const float4*>(&spy[j]);
            float4 vz = *reinterpret_cast<const float4*>(&spz[j]);
            float4 vs = *reinterpret_cast<const float4*>(&ssv[j]);
            m0a = fminf(m0a, fmaf(-2.0f, ax0 * vx.x + ay0 * vy.x + az0 * vz.x, vs.x));
            m0b = fminf(m0b, fmaf(-2.0f, ax0 * vx.y + ay0 * vy.y + az0 * vz.y, vs.y));
            m0a = fminf(m0a, fmaf(-2.0f, ax0 * vx.z + ay0 * vy.z + az0 * vz.z, vs.z));
            m0b = fminf(m0b, fmaf(-2.0f, ax0 * vx.w + ay0 * vy.w + az0 * vz.w, vs.w));
            m1a = fminf(m1a, fmaf(-2.0f, ax1 * vx.x + ay1 * vy.x + az1 * vz.x, vs.x));
            m1b = fminf(m1b, fmaf(-2.0f, ax1 * vx.y + ay1 * vy.y + az1 * vz.y, vs.y));
            m1a = fminf(m1a, fmaf(-2.0f, ax1 * vx.z + ay1 * vy.z + az1 * vz.z, vs.z));
            m1b = fminf(m1b, fmaf(-2.0f, ax1 * vx.w + ay1 * vy.w + az1 * vz.w, vs.w));
        }
        float* wrow = ws + WS_ROW + ((size_t)bh * QJ + qj) * NN + qi * CI;
        wrow[tid]      = r0 + fminf(m0a, m0b);
        wrow[tid + TB] = r1 + fminf(m1a, m1b);
    }

    // ---- Pass B: col-min partials. Thread owns sample j_local = tid, tid+TB. ----
    {
        float bx0 = spx[tid],      by0 = spy[tid],      bz0 = spz[tid],      s0 = ssv[tid];
        float bx1 = spx[tid + TB], by1 = spy[tid + TB], bz1 = spz[tid + TB], s1 = ssv[tid + TB];
        float m0a = 3.4e38f, m0b = 3.4e38f, m1a = 3.4e38f, m1b = 3.4e38f;
        for (int i = 0; i < CI; i += 4) {
            float4 vx = *reinterpret_cast<const float4*>(&rfx[i]);
            float4 vy = *reinterpret_cast<const float4*>(&rfy[i]);
            float4 vz = *reinterpret_cast<const float4*>(&rfz[i]);
            float4 vr = *reinterpret_cast<const float4*>(&rrv[i]);
            m0a = fminf(m0a, fmaf(-2.0f, bx0 * vx.x + by0 * vy.x + bz0 * vz.x, vr.x));
            m0b = fminf(m0b, fmaf(-2.0f, bx0 * vx.y + by0 * vy.y + bz0 * vz.y, vr.y));
            m0a = fminf(m0a, fmaf(-2.0f, bx0 * vx.z + by0 * vy.z + bz0 * vz.z, vr.z));
            m0b = fminf(m0b, fmaf(-2.0f, bx0 * vx.w + by0 * vy.w + bz0 * vz.w, vr.w));
            m1a = fminf(m1a, fmaf(-2.0f, bx1 * vx.x + by1 * vy.x + bz1 * vz.x, vr.x));
            m1b = fminf(m1b, fmaf(-2.0f, bx1 * vx.y + by1 * vy.y + bz1 * vz.y, vr.y));
            m1a = fminf(m1a, fmaf(-2.0f, bx1 * vx.z + by1 * vy.z + bz1 * vz.z, vr.z));
            m1b = fminf(m1b, fmaf(-2.0f, bx1 * vx.w + by1 * vy.w + bz1 * vz.w, vr.w));
        }
        float* wcol = ws + WS_COL + ((size_t)bh * QI + qi) * NN + qj * CJ;
        wcol[tid]      = s0 + fminf(m0a, m0b);
        wcol[tid + TB] = s1 + fminf(m1a, m1b);
    }
}

// ---------------------------------------------------------------------------
// Combine partials: min over chunks, sum over points -> sde sum per (b,h).
// ---------------------------------------------------------------------------
__global__ __launch_bounds__(TB) void reduce_kernel(float* __restrict__ ws)
{
    const int bh  = blockIdx.x;
    const int tid = threadIdx.x;
    const float* row = ws + WS_ROW + (size_t)bh * QJ * NN;
    const float* col = ws + WS_COL + (size_t)bh * QI * NN;
    float s = 0.0f;
    for (int i = tid; i < NN; i += TB) {
        s += fminf(row[i], row[NN + i]);
        s += fminf(col[i], col[NN + i]);
    }
    for (int off = 32; off; off >>= 1) s += __shfl_down(s, off, 64);
    __shared__ float wsum[TB / 64];
    if ((tid & 63) == 0) wsum[tid >> 6] = s;
    __syncthreads();
    if (tid == 0) {
        float t = 0.0f;
        for (int w = 0; w < TB / 64; ++w) t += wsum[w];
        ws[bh] = t;
    }
}

// ---------------------------------------------------------------------------
// Fallback chamfer (proven, needs only 512 B ws): used if ws_size too small.
// ---------------------------------------------------------------------------
#define QQ 2
__global__ __launch_bounds__(TB) void chamfer_fb_kernel(
    const float* __restrict__ y_pred,
    const float* __restrict__ sp,
    float* __restrict__ sde_acc)
{
    __shared__ __align__(16) float spx[NN], spy[NN], spz[NN];
    __shared__ __align__(16) float rfx[NN], rfy[NN], rfz[NN];
    __shared__ float wsum[TB / 64];

    const int blk = blockIdx.x;
    const int q   = blk % QQ;
    const int bh  = blk / QQ;
    const int b   = bh / HH;
    const int tid = threadIdx.x;

    float pnx = y_pred[bh * 4 + 0];
    float pny = y_pred[bh * 4 + 1];
    float pnz = y_pred[bh * 4 + 2];
    float pd  = y_pred[bh * 4 + 3];
    float inv = 1.0f / sqrtf(pnx * pnx + pny * pny + pnz * pnz);
    pnx *= inv; pny *= inv; pnz *= inv;

    const float* spb = sp + (size_t)b * NN * 3;
    for (int p = tid; p < NN; p += TB) {
        float x = spb[p * 3 + 0];
        float y = spb[p * 3 + 1];
        float z = spb[p * 3 + 2];
        spx[p] = x; spy[p] = y; spz[p] = z;
        float proj = x * pnx + y * pny + z * pnz + pd;
        rfx[p] = x - 2.0f * proj * pnx;
        rfy[p] = y - 2.0f * proj * pny;
        rfz[p] = z - 2.0f * proj * pnz;
    }
    __syncthreads();

    const int CH = NN / QQ;
    float local = 0.0f;

    {
        int i0 = q * CH + tid, i1 = i0 + TB;
        float ax = rfx[i0], ay = rfy[i0], az = rfz[i0];
        float bx = rfx[i1], by = rfy[i1], bz = rfz[i1];
        float m0 = 3.4e38f, m1 = 3.4e38f;
        for (int j = 0; j < NN; j += 4) {
            float4 vx = *reinterpret_cast<const float4*>(&spx[j]);
            float4 vy = *reinterpret_cast<const float4*>(&spy[j]);
            float4 vz = *reinterpret_cast<const float4*>(&spz[j]);
            float dx, dy, dz;
            dx = ax - vx.x; dy = ay - vy.x; dz = az - vz.x; m0 = fminf(m0, dx*dx + dy*dy + dz*dz);
            dx = ax - vx.y; dy = ay - vy.y; dz = az - vz.y; m0 = fminf(m0, dx*dx + dy*dy + dz*dz);
            dx = ax - vx.z; dy = ay - vy.z; dz = az - vz.z; m0 = fminf(m0, dx*dx + dy*dy + dz*dz);
            dx = ax - vx.w; dy = ay - vy.w; dz = az - vz.w; m0 = fminf(m0, dx*dx + dy*dy + dz*dz);
            dx = bx - vx.x; dy = by - vy.x; dz = bz - vz.x; m1 = fminf(m1, dx*dx + dy*dy + dz*dz);
            dx = bx - vx.y; dy = by - vy.y; dz = bz - vz.y; m1 = fminf(m1, dx*dx + dy*dy + dz*dz);
            dx = bx - vx.z; dy = by - vy.z; dz = bz - vz.z; m1 = fminf(m1, dx*dx + dy*dy + dz*dz);
            dx = bx - vx.w; dy = by - vy.w; dz = bz - vz.w; m1 = fminf(m1, dx*dx + dy*dy + dz*dz);
        }
        local += m0 + m1;
    }
    {
        int j0 = q * CH + tid, j1 = j0 + TB;
        float ax = spx[j0], ay = spy[j0], az = spz[j0];
        float bx = spx[j1], by = spy[j1], bz = spz[j1];
        float m0 = 3.4e38f, m1 = 3.4e38f;
        for (int i = 0; i < NN; i += 4) {
            float4 vx = *reinterpret_cast<const float4*>(&rfx[i]);
            float4 vy = *reinterpret_cast<const float4*>(&rfy[i]);
            float4 vz = *reinterpret_cast<const float4*>(&rfz[i]);
            float dx, dy, dz;
            dx = ax - vx.x; dy = ay - vy.x; dz = az - vz.x; m0 = fminf(m0, dx*dx + dy*dy + dz*dz);
            dx = ax - vx.y; dy = ay - vy.y; dz = az - vz.y; m0 = fminf(m0, dx*dx + dy*dy + dz*dz);
            dx = ax - vx.z; dy = ay - vy.z; dz = az - vz.z; m0 = fminf(m0, dx*dx + dy*dy + dz*dz);
            dx = ax - vx.w; dy = ay - vy.w; dz = az - vz.w; m0 = fminf(m0, dx*dx + dy*dy + dz*dz);
            dx = bx - vx.x; dy = by - vy.x; dz = bz - vz.x; m1 = fminf(m1, dx*dx + dy*dy + dz*dz);
            dx = bx - vx.y; dy = by - vy.y; dz = bz - vz.y; m1 = fminf(m1, dx*dx + dy*dy + dz*dz);
            dx = bx - vx.z; dy = by - vy.z; dz = bz - vz.z; m1 = fminf(m1, dx*dx + dy*dy + dz*dz);
            dx = bx - vx.w; dy = by - vy.w; dz = bz - vz.w; m1 = fminf(m1, dx*dx + dy*dy + dz*dz);
        }
        local += m0 + m1;
    }

    for (int off = 32; off; off >>= 1) local += __shfl_down(local, off, 64);
    int wid = tid >> 6, lane = tid & 63;
    if (lane == 0) wsum[wid] = local;
    __syncthreads();
    if (tid == 0) {
        float t = 0.0f;
        for (int w = 0; w < TB / 64; ++w) t += wsum[w];
        atomicAdd(&sde_acc[bh], t);
    }
}

// ---------------------------------------------------------------------------
// Finalize: centroid, conf, angle-NMS, stable rank, write output.
// sde_acc holds raw sums; divided by NN here.
// ---------------------------------------------------------------------------
__global__ __launch_bounds__(64) void finalize_kernel(
    const float* __restrict__ sde_acc,
    const float* __restrict__ y_pred,
    const float* __restrict__ sp,
    float* __restrict__ out)
{
    const int b   = blockIdx.x;
    const int tid = threadIdx.x;

    const float* spb = sp + (size_t)b * NN * 3;
    float sx = 0.0f, sy = 0.0f, sz = 0.0f;
    for (int p = tid; p < NN; p += 64) {
        sx += spb[p * 3 + 0];
        sy += spb[p * 3 + 1];
        sz += spb[p * 3 + 2];
    }
    for (int off = 32; off; off >>= 1) {
        sx += __shfl_down(sx, off, 64);
        sy += __shfl_down(sy, off, 64);
        sz += __shfl_down(sz, off, 64);
    }
    sx = __shfl(sx, 0, 64); sy = __shfl(sy, 0, 64); sz = __shfl(sz, 0, 64);
    const float cmx = sx / NN, cmy = sy / NN, cmz = sz / NN;

    __shared__ float sde_s[HH], nx_s[HH], ny_s[HH], nz_s[HH], d_s[HH], conf_s[HH];
    __shared__ int keep_s[HH];

    if (tid < HH) {
        int h = tid;
        float nx = y_pred[(b * HH + h) * 4 + 0];
        float ny = y_pred[(b * HH + h) * 4 + 1];
        float nz = y_pred[(b * HH + h) * 4 + 2];
        float d  = y_pred[(b * HH + h) * 4 + 3];
        float inv = 1.0f / sqrtf(nx * nx + ny * ny + nz * nz);
        nx *= inv; ny *= inv; nz *= inv;
        nx_s[h] = nx; ny_s[h] = ny; nz_s[h] = nz; d_s[h] = d;
        sde_s[h] = sde_acc[b * HH + h] * (1.0f / NN);
    }
    __syncthreads();

    if (tid < HH) {
        int h = tid;
        float mn = sde_s[0], mx = sde_s[0];
        for (int g = 1; g < HH; ++g) {
            mn = fminf(mn, sde_s[g]);
            mx = fmaxf(mx, sde_s[g]);
        }
        float sde  = sde_s[h];
        float conf = 1.0f - (sde - mn) / fabsf(mx - mn);
        conf_s[h]  = conf;
        bool valid = (sde <= 10.0f);
        bool sup   = false;
        if (valid) {
            for (int g = 0; g < HH; ++g) {
                if (g == h) continue;
                float c = nx_s[h] * nx_s[g] + ny_s[h] * ny_s[g] + nz_s[h] * nz_s[g];
                c = fminf(1.0f, fmaxf(-1.0f, c));
                float ang = acosf(c) * 57.29577951308232f;
                bool close = (ang < 30.0f) || (180.0f - ang < 30.0f);
                if (close && (sde_s[g] <= 10.0f) && (sde >= sde_s[g])) sup = true;
            }
        }
        keep_s[h] = (valid && !sup) ? 1 : 0;
    }
    __syncthreads();

    if (tid < HH) {
        int h = tid;
        float keyh = keep_s[h] ? conf_s[h] : -INFINITY;
        int pos = 0;
        for (int g = 0; g < HH; ++g) {
            float keyg = keep_s[g] ? conf_s[g] : -INFINITY;
            if (keyg > keyh || (keyg == keyh && g < h)) ++pos;
        }
        float nx = nx_s[h], ny = ny_s[h], nz = nz_s[h];
        float t  = nx * cmx + ny * cmy + nz * cmz + d_s[h];
        float px = cmx - t * nx, py = cmy - t * ny, pz = cmz - t * nz;

        float* o = out + (size_t)(b * HH + pos) * 8;
        if (keep_s[h]) {
            o[0] = nx; o[1] = ny; o[2] = nz;
            o[3] = px; o[4] = py; o[5] = pz;
            o[6] = conf_s[h];
            o[7] = sde_s[h];
        } else {
            for (int c = 0; c < 8; ++c) o[c] = 0.0f;
        }
    }
}

extern "C" void kernel_launch(void* const* d_in, const int* in_sizes, int n_in,
                              void* d_out, int out_size, void* d_ws, size_t ws_size,
                              hipStream_t stream) {
    const float* y_pred = (const float*)d_in[0];   // (8,16,4) f32
    const float* sp     = (const float*)d_in[1];   // (8,1024,3) f32
    float* out          = (float*)d_out;           // (8,16,8) f32
    float* ws           = (float*)d_ws;

    if (ws_size >= (size_t)WS_FLOATS * sizeof(float)) {
        // split path: partial mins to ws (every slot written; no init needed)
        chamfer_split_kernel<<<dim3(BB * HH * QI * QJ), dim3(TB), 0, stream>>>(y_pred, sp, ws);
        reduce_kernel<<<dim3(BB * HH), dim3(TB), 0, stream>>>(ws);
        finalize_kernel<<<dim3(BB), dim3(64), 0, stream>>>(ws, y_pred, sp, out);
    } else {
        hipMemsetAsync(ws, 0, BB * HH * sizeof(float), stream);
        chamfer_fb_kernel<<<dim3(BB * HH * QQ), dim3(TB), 0, stream>>>(y_pred, sp, ws);
        finalize_kernel<<<dim3(BB), dim3(64), 0, stream>>>(ws, y_pred, sp, out);
    }
}

// Round 4
// 94.998 us; speedup vs baseline: 1.4682x; 1.1065x over previous
//
#include <hip/hip_runtime.h>
#include <math.h>

#define BB 8
#define HH 16
#define NN 1024
#define TB 256
#define CHUNK 256                 // own-points per block
#define NCHUNK (NN / CHUNK)       // 4
#define SUBS (2 * NCHUNK)         // 8 blocks per (b,h): pass{A,B} x 4 chunks

// ws layout: ws[blk] = partial sde sum for blk = bh*SUBS + sub. 1024 floats.

// ---------------------------------------------------------------------------
// chamfer: block (bh, pass, chunk). Own side in registers (1 pt/thread,
// coords premultiplied by -2); scan side staged in LDS as float4{x,y,z,sq}.
// key_scan = fma(mx,qx, fma(my,qy, fma(mz,qz, q.sq)));  res = own_sq + min.
// Pass A: own = reflected points, scan = samples. Pass B: own = samples,
// scan = reflected. Block writes one float: sum over its 256 own-points.
// ---------------------------------------------------------------------------
__global__ __launch_bounds__(TB, 4) void chamfer_kernel(
    const float* __restrict__ y_pred,
    const float* __restrict__ sp,
    float* __restrict__ ws)
{
    __shared__ __align__(16) float4 pts[NN];     // 16 KB
    __shared__ float wsum[TB / 64];

    const int blk   = blockIdx.x;
    const int bh    = blk / SUBS;
    const int sub   = blk % SUBS;
    const int passB = sub >> 2;          // 0: row pass (refl vs samples)
    const int chunk = sub & 3;
    const int b     = bh >> 4;           // HH = 16
    const int tid   = threadIdx.x;

    float pnx = y_pred[bh * 4 + 0];
    float pny = y_pred[bh * 4 + 1];
    float pnz = y_pred[bh * 4 + 2];
    float pd  = y_pred[bh * 4 + 3];
    float inv = 1.0f / sqrtf(pnx * pnx + pny * pny + pnz * pnz);
    pnx *= inv; pny *= inv; pnz *= inv;

    const float* spb = sp + (size_t)b * NN * 3;

    // stage the SCAN side (all 1024 points): pass A scans raw samples,
    // pass B scans reflected points.
    for (int p = tid; p < NN; p += TB) {
        float x = spb[p * 3 + 0];
        float y = spb[p * 3 + 1];
        float z = spb[p * 3 + 2];
        if (passB) {
            float proj = x * pnx + y * pny + z * pnz + pd;
            x -= 2.0f * proj * pnx;
            y -= 2.0f * proj * pny;
            z -= 2.0f * proj * pnz;
        }
        pts[p] = make_float4(x, y, z, x * x + y * y + z * z);
    }

    // own point (registers)
    {
        const int pidx = chunk * CHUNK + tid;
        float x = spb[pidx * 3 + 0];
        float y = spb[pidx * 3 + 1];
        float z = spb[pidx * 3 + 2];
        if (!passB) {
            float proj = x * pnx + y * pny + z * pnz + pd;
            x -= 2.0f * proj * pnx;
            y -= 2.0f * proj * pny;
            z -= 2.0f * proj * pnz;
        }
        const float own_sq = x * x + y * y + z * z;
        const float mx = -2.0f * x, my = -2.0f * y, mz = -2.0f * z;
        __syncthreads();

        float m0 = 3.4e38f, m1 = 3.4e38f, m2 = 3.4e38f, m3 = 3.4e38f;
        for (int j = 0; j < NN; j += 4) {
            float4 q0 = pts[j + 0];
            float4 q1 = pts[j + 1];
            float4 q2 = pts[j + 2];
            float4 q3 = pts[j + 3];
            m0 = fminf(m0, fmaf(mx, q0.x, fmaf(my, q0.y, fmaf(mz, q0.z, q0.w))));
            m1 = fminf(m1, fmaf(mx, q1.x, fmaf(my, q1.y, fmaf(mz, q1.z, q1.w))));
            m2 = fminf(m2, fmaf(mx, q2.x, fmaf(my, q2.y, fmaf(mz, q2.z, q2.w))));
            m3 = fminf(m3, fmaf(mx, q3.x, fmaf(my, q3.y, fmaf(mz, q3.z, q3.w))));
        }
        float local = own_sq + fminf(fminf(m0, m1), fminf(m2, m3));

        // block sum -> ws[blk]
        for (int off = 32; off; off >>= 1) local += __shfl_down(local, off, 64);
        if ((tid & 63) == 0) wsum[tid >> 6] = local;
    }
    __syncthreads();
    if (tid == 0) {
        float t = 0.0f;
        for (int w = 0; w < TB / 64; ++w) t += wsum[w];
        ws[blk] = t;
    }
}

// ---------------------------------------------------------------------------
// finalize: per batch — centroid, sde assembly from 8 partials per (b,h),
// conf, angle-NMS, stable rank, output write.
// ---------------------------------------------------------------------------
__global__ __launch_bounds__(64) void finalize_kernel(
    const float* __restrict__ ws,
    const float* __restrict__ y_pred,
    const float* __restrict__ sp,
    float* __restrict__ out)
{
    const int b   = blockIdx.x;
    const int tid = threadIdx.x;

    const float* spb = sp + (size_t)b * NN * 3;
    float sx = 0.0f, sy = 0.0f, sz = 0.0f;
    for (int p = tid; p < NN; p += 64) {
        sx += spb[p * 3 + 0];
        sy += spb[p * 3 + 1];
        sz += spb[p * 3 + 2];
    }
    for (int off = 32; off; off >>= 1) {
        sx += __shfl_down(sx, off, 64);
        sy += __shfl_down(sy, off, 64);
        sz += __shfl_down(sz, off, 64);
    }
    sx = __shfl(sx, 0, 64); sy = __shfl(sy, 0, 64); sz = __shfl(sz, 0, 64);
    const float cmx = sx / NN, cmy = sy / NN, cmz = sz / NN;

    __shared__ float sde_s[HH], nx_s[HH], ny_s[HH], nz_s[HH], d_s[HH], conf_s[HH];
    __shared__ int keep_s[HH];

    if (tid < HH) {
        int h = tid;
        float nx = y_pred[(b * HH + h) * 4 + 0];
        float ny = y_pred[(b * HH + h) * 4 + 1];
        float nz = y_pred[(b * HH + h) * 4 + 2];
        float d  = y_pred[(b * HH + h) * 4 + 3];
        float inv = 1.0f / sqrtf(nx * nx + ny * ny + nz * nz);
        nx *= inv; ny *= inv; nz *= inv;
        nx_s[h] = nx; ny_s[h] = ny; nz_s[h] = nz; d_s[h] = d;
        const float* wp = ws + (size_t)(b * HH + h) * SUBS;
        float s = 0.0f;
        for (int k = 0; k < SUBS; ++k) s += wp[k];
        sde_s[h] = s * (1.0f / NN);
    }
    __syncthreads();

    if (tid < HH) {
        int h = tid;
        float mn = sde_s[0], mx = sde_s[0];
        for (int g = 1; g < HH; ++g) {
            mn = fminf(mn, sde_s[g]);
            mx = fmaxf(mx, sde_s[g]);
        }
        float sde  = sde_s[h];
        float conf = 1.0f - (sde - mn) / fabsf(mx - mn);
        conf_s[h]  = conf;
        bool valid = (sde <= 10.0f);
        bool sup   = false;
        if (valid) {
            for (int g = 0; g < HH; ++g) {
                if (g == h) continue;
                float c = nx_s[h] * nx_s[g] + ny_s[h] * ny_s[g] + nz_s[h] * nz_s[g];
                c = fminf(1.0f, fmaxf(-1.0f, c));
                float ang = acosf(c) * 57.29577951308232f;
                bool close = (ang < 30.0f) || (180.0f - ang < 30.0f);
                if (close && (sde_s[g] <= 10.0f) && (sde >= sde_s[g])) sup = true;
            }
        }
        keep_s[h] = (valid && !sup) ? 1 : 0;
    }
    __syncthreads();

    if (tid < HH) {
        int h = tid;
        // stable descending rank on key = keep ? conf : -inf (jnp.argsort(-key))
        float keyh = keep_s[h] ? conf_s[h] : -INFINITY;
        int pos = 0;
        for (int g = 0; g < HH; ++g) {
            float keyg = keep_s[g] ? conf_s[g] : -INFINITY;
            if (keyg > keyh || (keyg == keyh && g < h)) ++pos;
        }
        float nx = nx_s[h], ny = ny_s[h], nz = nz_s[h];
        float t  = nx * cmx + ny * cmy + nz * cmz + d_s[h];
        float px = cmx - t * nx, py = cmy - t * ny, pz = cmz - t * nz;

        float* o = out + (size_t)(b * HH + pos) * 8;
        if (keep_s[h]) {
            o[0] = nx; o[1] = ny; o[2] = nz;
            o[3] = px; o[4] = py; o[5] = pz;
            o[6] = conf_s[h];
            o[7] = sde_s[h];
        } else {
            for (int c = 0; c < 8; ++c) o[c] = 0.0f;
        }
    }
}

extern "C" void kernel_launch(void* const* d_in, const int* in_sizes, int n_in,
                              void* d_out, int out_size, void* d_ws, size_t ws_size,
                              hipStream_t stream) {
    const float* y_pred = (const float*)d_in[0];   // (8,16,4) f32
    const float* sp     = (const float*)d_in[1];   // (8,1024,3) f32
    float* out          = (float*)d_out;           // (8,16,8) f32
    float* ws           = (float*)d_ws;            // 1024 floats, all written

    chamfer_kernel<<<dim3(BB * HH * SUBS), dim3(TB), 0, stream>>>(y_pred, sp, ws);
    finalize_kernel<<<dim3(BB), dim3(64), 0, stream>>>(ws, y_pred, sp, out);
}